// Round 1
// baseline (252.282 us; speedup 1.0000x reference)
//
#include <hip/hip_runtime.h>

typedef __attribute__((ext_vector_type(8))) short s8bf;     // 8 bf16 payload
typedef __attribute__((ext_vector_type(8))) __bf16 v8bf;    // MFMA operand type
typedef __attribute__((ext_vector_type(4))) float f32x4;

__device__ __forceinline__ short f2bf(float f) {
  union { float f; unsigned u; } v; v.f = f;
  unsigned r = v.u + 0x7FFFu + ((v.u >> 16) & 1u);  // RNE
  return (short)(r >> 16);
}

__device__ __forceinline__ f32x4 mfma16(s8bf a, s8bf b, f32x4 c) {
  return __builtin_amdgcn_mfma_f32_16x16x32_bf16(
      __builtin_bit_cast(v8bf, a), __builtin_bit_cast(v8bf, b), c, 0, 0, 0);
}

__device__ __forceinline__ void gl_lds16(const void* g, void* l) {
  __builtin_amdgcn_global_load_lds(
      (const __attribute__((address_space(1))) unsigned*)g,
      (__attribute__((address_space(3))) unsigned*)l, 16, 0, 0);
}

// ---------------- f32 -> bf16 cast (vectorized) ----------------
__global__ void cvt_f32_bf16_k(const float* __restrict__ in, short* __restrict__ out, int n4) {
  int i = blockIdx.x * 256 + threadIdx.x;
  if (i < n4) {
    float4 v = ((const float4*)in)[i];
    short4 o;
    o.x = f2bf(v.x); o.y = f2bf(v.y); o.z = f2bf(v.z); o.w = f2bf(v.w);
    ((short4*)out)[i] = o;
  }
}

// ---------------- W [K][N] f32 -> Wt [N][K] bf16 ----------------
__global__ void transp_bf16_k(const float* __restrict__ W, short* __restrict__ Wt, int K, int N) {
  __shared__ float t[32][33];
  int k0 = blockIdx.x * 32, n0 = blockIdx.y * 32;
  int tx = threadIdx.x & 31, ty = threadIdx.x >> 5;  // ty 0..7
  #pragma unroll
  for (int i = 0; i < 4; ++i)
    t[ty + i * 8][tx] = W[(size_t)(k0 + ty + i * 8) * N + n0 + tx];
  __syncthreads();
  #pragma unroll
  for (int i = 0; i < 4; ++i)
    Wt[(size_t)(n0 + ty + i * 8) * K + k0 + tx] = f2bf(t[tx][ty + i * 8]);
}

// ---------------- mask -> additive bias, dtype-robust ----------------
__global__ void mask_bias_k(const void* __restrict__ mask, float* __restrict__ bias, int n) {
  __shared__ int fmt;  // 0=u8, 1=i32, 2=f32
  const unsigned char* p8 = (const unsigned char*)mask;
  if (threadIdx.x == 0) {
    // probe only first 256 bytes (in-bounds under every candidate dtype)
    const float* pf = (const float*)mask;
    int allf = 1, anyone = 0;
    for (int i = 0; i < 64; ++i) {
      float f = pf[i];
      if (f != 0.0f && f != 1.0f) allf = 0;
      if (f == 1.0f) anyone = 1;
    }
    int any13 = 0;
    for (int i = 0; i < 256; ++i) if ((i & 3) && p8[i]) any13 = 1;
    fmt = (allf && anyone) ? 2 : (any13 ? 0 : 1);
  }
  __syncthreads();
  int j = threadIdx.x;
  if (j < n) {
    int m;
    if (fmt == 2)      m = (((const float*)mask)[j] != 0.0f);
    else if (fmt == 0) m = (p8[j] != 0);
    else               m = (((const int*)mask)[j] != 0);
    bias[j] = m ? 0.0f : -1e30f;
  }
}

// ---------------- m97-style bf16 GEMM, A[M][K] @ Bt[N][K]^T ----------------
// MODE 0: store bf16   1: store f32   2: atomicAdd f32   3: atomicAdd f32, V-transposed layout
template<int MODE>
__global__ __launch_bounds__(256, 2) void gemm_bt_k(
    const short* __restrict__ A, const short* __restrict__ Bt, void* __restrict__ C,
    int M, int N, int K, int kchunk)
{
  __shared__ short aT[128 * 32];  // [m][k]
  __shared__ short bT[128 * 32];  // [n][k]
  const int m0 = blockIdx.x * 128, n0 = blockIdx.y * 128;
  const int wid = threadIdx.x >> 6, lane = threadIdx.x & 63;
  const int wr = wid >> 1, wc = wid & 1;
  const int k_lo = blockIdx.z * kchunk, k_hi = k_lo + kchunk;
  f32x4 acc[4][4] = {};
  const int srow = wid * 32 + (lane >> 2);
  const int skoff = (lane & 3) * 8;
  const short* aG = A + (size_t)(m0 + srow) * K + skoff;
  const short* bG = Bt + (size_t)(n0 + srow) * K + skoff;
  char* aL = (char*)aT + wid * 2048;
  char* bL = (char*)bT + wid * 2048;
  const short* ap = aT + (wr * 64 + (lane & 15)) * 32 + (lane >> 4) * 8;
  const short* bp = bT + (wc * 64 + (lane & 15)) * 32 + (lane >> 4) * 8;
  for (int k0 = k_lo; k0 < k_hi; k0 += 32) {
    gl_lds16(aG + k0, aL);
    gl_lds16(aG + (size_t)16 * K + k0, aL + 1024);
    gl_lds16(bG + k0, bL);
    gl_lds16(bG + (size_t)16 * K + k0, bL + 1024);
    __syncthreads();
    s8bf af[4], bf[4];
    #pragma unroll
    for (int i = 0; i < 4; ++i) {
      af[i] = *(const s8bf*)(ap + i * 512);
      bf[i] = *(const s8bf*)(bp + i * 512);
    }
    #pragma unroll
    for (int mi = 0; mi < 4; ++mi)
      #pragma unroll
      for (int ni = 0; ni < 4; ++ni)
        acc[mi][ni] = mfma16(af[mi], bf[ni], acc[mi][ni]);
    __syncthreads();
  }
  const int r0 = m0 + wr * 64 + ((lane >> 4) << 2);
  const int c0 = n0 + wc * 64 + (lane & 15);
  #pragma unroll
  for (int mi = 0; mi < 4; ++mi)
    #pragma unroll
    for (int ni = 0; ni < 4; ++ni)
      #pragma unroll
      for (int v = 0; v < 4; ++v) {
        int row = r0 + mi * 16 + v, col = c0 + ni * 16;
        float val = acc[mi][ni][v];
        if (MODE == 0) ((short*)C)[(size_t)row * N + col] = f2bf(val);
        else if (MODE == 1) ((float*)C)[(size_t)row * N + col] = val;
        else if (MODE == 2) atomicAdd((float*)C + ((size_t)row * N + col), val);
        else { int bb = row >> 7, j = row & 127;
               atomicAdd((float*)C + ((size_t)(bb * 1536 + col)) * 128 + j, val); }
      }
}

// ---------------- fused attention for one (i-tile=128, head, batch) ----------------
__global__ __launch_bounds__(256, 2) void attn_k(
    const short* __restrict__ q, const short* __restrict__ kk,
    const short* __restrict__ vt, const float* __restrict__ bias,
    short* __restrict__ ao)
{
  __shared__ short kT[128 * 64];     // [j][d], XOR-swizzled rows
  __shared__ short vT[64 * 128];     // [d][j], XOR-swizzled rows
  __shared__ short pT[4][32 * 128];  // per-wave P, XOR-swizzled rows
  const int it = blockIdx.x, h = blockIdx.y, b = blockIdx.z;
  const int wid = threadIdx.x >> 6, lane = threadIdx.x & 63;
  const int i0 = it * 128;

  // stage K: dest linear, source pre-swizzled (rule #21)
  #pragma unroll
  for (int c = 0; c < 4; ++c) {
    int seg = c * 256 + wid * 64 + lane;
    int j = seg >> 3, ds = seg & 7;
    int dsrc = ds ^ (j & 7);
    gl_lds16(kk + ((size_t)(b * 128 + j) * 1536 + h * 64 + dsrc * 8),
             (char*)kT + c * 4096 + wid * 1024);
  }
  // stage V^T
  #pragma unroll
  for (int c = 0; c < 4; ++c) {
    int seg = c * 256 + wid * 64 + lane;
    int d = seg >> 4, js = seg & 15;
    int jsrc = js ^ (d & 7);
    gl_lds16(vt + ((size_t)(b * 1536 + h * 64 + d) * 128 + jsrc * 8),
             (char*)vT + c * 4096 + wid * 1024);
  }

  // bias per lane-column (8 col-tiles)
  float bcol[8];
  #pragma unroll
  for (int nj = 0; nj < 8; ++nj) bcol[nj] = bias[b * 128 + nj * 16 + (lane & 15)];

  // Q fragments from global (rows this wave owns)
  s8bf qf[2][2];
  #pragma unroll
  for (int mi = 0; mi < 2; ++mi)
    #pragma unroll
    for (int ks = 0; ks < 2; ++ks) {
      size_t row = (size_t)(b * 4096 + i0 + wid * 32 + mi * 16 + (lane & 15));
      qf[mi][ks] = *(const s8bf*)(q + row * 1536 + h * 64 + ks * 32 + (lane >> 4) * 8);
    }
  __syncthreads();

  // S = Q K^T
  f32x4 s[2][8] = {};
  #pragma unroll
  for (int ks = 0; ks < 2; ++ks) {
    int kd = ks * 32 + (lane >> 4) * 8;
    #pragma unroll
    for (int nj = 0; nj < 8; ++nj) {
      int j = nj * 16 + (lane & 15);
      s8bf kb = *(const s8bf*)((const char*)kT + j * 128 + ((2 * kd) ^ ((j & 7) << 4)));
      s[0][nj] = mfma16(qf[0][ks], kb, s[0][nj]);
      s[1][nj] = mfma16(qf[1][ks], kb, s[1][nj]);
    }
  }

  // masked softmax (rows live across the 16 lanes sharing lane>>4)
  float sm[2][4];
  #pragma unroll
  for (int mi = 0; mi < 2; ++mi)
    #pragma unroll
    for (int v = 0; v < 4; ++v) {
      float mx = -1e30f;
      #pragma unroll
      for (int nj = 0; nj < 8; ++nj) {
        float sv = s[mi][nj][v] * 0.125f + bcol[nj];
        s[mi][nj][v] = sv;
        mx = fmaxf(mx, sv);
      }
      mx = fmaxf(mx, __shfl_xor(mx, 1));
      mx = fmaxf(mx, __shfl_xor(mx, 2));
      mx = fmaxf(mx, __shfl_xor(mx, 4));
      mx = fmaxf(mx, __shfl_xor(mx, 8));
      float ss = 0.f;
      #pragma unroll
      for (int nj = 0; nj < 8; ++nj) {
        float p = __expf(s[mi][nj][v] - mx);
        s[mi][nj][v] = p;
        ss += p;
      }
      ss += __shfl_xor(ss, 1);
      ss += __shfl_xor(ss, 2);
      ss += __shfl_xor(ss, 4);
      ss += __shfl_xor(ss, 8);
      sm[mi][v] = ss;
    }

  // P -> LDS (bf16, swizzled)
  #pragma unroll
  for (int mi = 0; mi < 2; ++mi)
    #pragma unroll
    for (int v = 0; v < 4; ++v) {
      int r = mi * 16 + ((lane >> 4) << 2) + v;
      char* base = (char*)&pT[wid][0] + r * 256;
      #pragma unroll
      for (int nj = 0; nj < 8; ++nj) {
        int j = nj * 16 + (lane & 15);
        *(short*)(base + ((2 * j) ^ ((r & 7) << 4))) = f2bf(s[mi][nj][v]);
      }
    }
  __syncthreads();

  // O = P V
  f32x4 o_[2][4] = {};
  #pragma unroll
  for (int ks = 0; ks < 4; ++ks) {
    int j = ks * 32 + (lane >> 4) * 8;
    s8bf pa[2];
    #pragma unroll
    for (int mi = 0; mi < 2; ++mi) {
      int r = mi * 16 + (lane & 15);
      pa[mi] = *(const s8bf*)((const char*)&pT[wid][0] + r * 256 + ((2 * j) ^ ((r & 7) << 4)));
    }
    #pragma unroll
    for (int dj = 0; dj < 4; ++dj) {
      int d = dj * 16 + (lane & 15);
      s8bf vb = *(const s8bf*)((const char*)vT + d * 256 + ((2 * j) ^ ((d & 7) << 4)));
      o_[0][dj] = mfma16(pa[0], vb, o_[0][dj]);
      o_[1][dj] = mfma16(pa[1], vb, o_[1][dj]);
    }
  }

  // normalize + store bf16 [b*n][h*64+d]
  #pragma unroll
  for (int mi = 0; mi < 2; ++mi)
    #pragma unroll
    for (int v = 0; v < 4; ++v) {
      int r = mi * 16 + ((lane >> 4) << 2) + v;
      float is = 1.0f / sm[mi][v];
      size_t row = (size_t)(b * 4096 + i0 + wid * 32 + r);
      #pragma unroll
      for (int dj = 0; dj < 4; ++dj) {
        int d = dj * 16 + (lane & 15);
        ao[row * 1536 + h * 64 + d] = f2bf(o_[mi][dj][v] * is);
      }
    }
}

extern "C" void kernel_launch(void* const* d_in, const int* in_sizes, int n_in,
                              void* d_out, int out_size, void* d_ws, size_t ws_size,
                              hipStream_t stream) {
  const float* x   = (const float*)d_in[0];
  const float* ctx = (const float*)d_in[1];
  const void*  msk = d_in[2];
  const float* Wq  = (const float*)d_in[3];
  const float* Wk  = (const float*)d_in[4];
  const float* Wv  = (const float*)d_in[5];
  const float* Wo  = (const float*)d_in[6];
  float* out = (float*)d_out;

  const int B = 2, NI = 4096, NT = 128, C = 1536, CC = 4096, H = 24;
  const int Mq = B * NI;  // 8192
  const int Mk = B * NT;  // 256

  size_t off = 0;
  auto carve = [&](size_t bytes) -> void* {
    void* p = (char*)d_ws + off;
    off += (bytes + 255) & ~(size_t)255;
    return p;
  };
  short* xbf   = (short*)carve((size_t)Mq * C * 2);   // reused as attn-out after Q-proj
  short* ctxbf = (short*)carve((size_t)Mk * CC * 2);
  short* WqT   = (short*)carve((size_t)C * C * 2);
  short* WkT   = (short*)carve((size_t)CC * C * 2);
  short* WvT   = (short*)carve((size_t)CC * C * 2);
  short* WoT   = (short*)carve((size_t)C * C * 2);
  short* qbf   = (short*)carve((size_t)Mq * C * 2);
  float* kf    = (float*)carve((size_t)Mk * C * 4);
  float* vtf   = (float*)carve((size_t)Mk * C * 4);   // contiguous after kf
  short* kbf   = (short*)carve((size_t)Mk * C * 2);
  short* vtbf  = (short*)carve((size_t)Mk * C * 2);
  float* bias  = (float*)carve(256 * 4);
  short* aout  = xbf;  // alias: x dead after Q-proj

  // pre-pass: casts + weight transposes + mask bias
  cvt_f32_bf16_k<<<(Mq * C / 4 + 255) / 256, 256, 0, stream>>>(x, xbf, Mq * C / 4);
  cvt_f32_bf16_k<<<(Mk * CC / 4 + 255) / 256, 256, 0, stream>>>(ctx, ctxbf, Mk * CC / 4);
  transp_bf16_k<<<dim3(C / 32, C / 32), 256, 0, stream>>>(Wq, WqT, C, C);
  transp_bf16_k<<<dim3(CC / 32, C / 32), 256, 0, stream>>>(Wk, WkT, CC, C);
  transp_bf16_k<<<dim3(CC / 32, C / 32), 256, 0, stream>>>(Wv, WvT, CC, C);
  transp_bf16_k<<<dim3(C / 32, C / 32), 256, 0, stream>>>(Wo, WoT, C, C);
  mask_bias_k<<<1, 256, 0, stream>>>(msk, bias, 256);
  hipMemsetAsync(kf, 0, (size_t)Mk * C * 4 * 2, stream);  // kf + vtf

  // Q projection
  gemm_bt_k<0><<<dim3(Mq / 128, C / 128, 1), 256, 0, stream>>>(xbf, WqT, qbf, Mq, C, C, C);
  // K, V projections (split-K=8, atomic f32; V transposed to [b][c][j])
  gemm_bt_k<2><<<dim3(Mk / 128, C / 128, 8), 256, 0, stream>>>(ctxbf, WkT, kf, Mk, C, CC, 512);
  gemm_bt_k<3><<<dim3(Mk / 128, C / 128, 8), 256, 0, stream>>>(ctxbf, WvT, vtf, Mk, C, CC, 512);
  cvt_f32_bf16_k<<<(Mk * C / 4 + 255) / 256, 256, 0, stream>>>(kf, kbf, Mk * C / 4);
  cvt_f32_bf16_k<<<(Mk * C / 4 + 255) / 256, 256, 0, stream>>>(vtf, vtbf, Mk * C / 4);

  // fused attention
  attn_k<<<dim3(NI / 128, H, B), 256, 0, stream>>>(qbf, kbf, vtbf, bias, aout);

  // output projection (f32 out)
  gemm_bt_k<1><<<dim3(Mq / 128, C / 128, 1), 256, 0, stream>>>(aout, WoT, out, Mq, C, C, C);
}

// Round 2
// 232.652 us; speedup vs baseline: 1.0844x; 1.0844x over previous
//
#include <hip/hip_runtime.h>

typedef __attribute__((ext_vector_type(8))) short s8bf;     // 8 bf16 payload
typedef __attribute__((ext_vector_type(8))) __bf16 v8bf;    // MFMA operand type
typedef __attribute__((ext_vector_type(4))) float f32x4;

__device__ __forceinline__ short f2bf(float f) {
  union { float f; unsigned u; } v; v.f = f;
  unsigned r = v.u + 0x7FFFu + ((v.u >> 16) & 1u);  // RNE
  return (short)(r >> 16);
}

__device__ __forceinline__ f32x4 mfma16(s8bf a, s8bf b, f32x4 c) {
  return __builtin_amdgcn_mfma_f32_16x16x32_bf16(
      __builtin_bit_cast(v8bf, a), __builtin_bit_cast(v8bf, b), c, 0, 0, 0);
}

__device__ __forceinline__ void gl_lds16(const void* g, void* l) {
  __builtin_amdgcn_global_load_lds(
      (const __attribute__((address_space(1))) unsigned*)g,
      (__attribute__((address_space(3))) unsigned*)l, 16, 0, 0);
}

// ---------------- f32 -> bf16 cast (vectorized) ----------------
__global__ void cvt_f32_bf16_k(const float* __restrict__ in, short* __restrict__ out, int n4) {
  int i = blockIdx.x * 256 + threadIdx.x;
  if (i < n4) {
    float4 v = ((const float4*)in)[i];
    short4 o;
    o.x = f2bf(v.x); o.y = f2bf(v.y); o.z = f2bf(v.z); o.w = f2bf(v.w);
    ((short4*)out)[i] = o;
  }
}

// ---------------- W [K][N] f32 -> Wt [N][K] bf16 ----------------
__global__ void transp_bf16_k(const float* __restrict__ W, short* __restrict__ Wt, int K, int N) {
  __shared__ float t[32][33];
  int k0 = blockIdx.x * 32, n0 = blockIdx.y * 32;
  int tx = threadIdx.x & 31, ty = threadIdx.x >> 5;  // ty 0..7
  #pragma unroll
  for (int i = 0; i < 4; ++i)
    t[ty + i * 8][tx] = W[(size_t)(k0 + ty + i * 8) * N + n0 + tx];
  __syncthreads();
  #pragma unroll
  for (int i = 0; i < 4; ++i)
    Wt[(size_t)(n0 + ty + i * 8) * K + k0 + tx] = f2bf(t[tx][ty + i * 8]);
}

// ---------------- mask -> additive bias, dtype-robust ----------------
__global__ void mask_bias_k(const void* __restrict__ mask, float* __restrict__ bias, int n) {
  __shared__ int fmt;  // 0=u8, 1=i32, 2=f32
  const unsigned char* p8 = (const unsigned char*)mask;
  if (threadIdx.x == 0) {
    const float* pf = (const float*)mask;
    int allf = 1, anyone = 0;
    for (int i = 0; i < 64; ++i) {
      float f = pf[i];
      if (f != 0.0f && f != 1.0f) allf = 0;
      if (f == 1.0f) anyone = 1;
    }
    int any13 = 0;
    for (int i = 0; i < 256; ++i) if ((i & 3) && p8[i]) any13 = 1;
    fmt = (allf && anyone) ? 2 : (any13 ? 0 : 1);
  }
  __syncthreads();
  int j = threadIdx.x;
  if (j < n) {
    int m;
    if (fmt == 2)      m = (((const float*)mask)[j] != 0.0f);
    else if (fmt == 0) m = (p8[j] != 0);
    else               m = (((const int*)mask)[j] != 0);
    bias[j] = m ? 0.0f : -1e30f;
  }
}

// ======== pipelined 256x192 GEMM, counted vmcnt, T2 swizzle, T5 setprio ========
// A[M][K] bf16 @ Bt[N][K]^T -> C[M][N].  MODE 0: bf16 store, 1: f32 store.
// BK=32, 2 LDS buffers (28KB each), stage depth 2, 8 waves (2x4), wave tile 128x48.
#define SWZ(o) ((o) ^ ((((o) >> 7) & 7) << 4))
template<int MODE>
__global__ __launch_bounds__(512, 2) void gemm8p_k(
    const short* __restrict__ A, const short* __restrict__ Bt, void* __restrict__ C,
    int M, int N, int K)
{
  __shared__ short lds[2 * 14336];  // per buf: A 16KB (256x32) + B 12KB (192x32)
  char* ldsb = (char*)lds;
  const int tid = threadIdx.x, wid = tid >> 6, lane = tid & 63;
  const int nbx = N / 192;
  const int nwg = gridDim.x;
  const int bid = blockIdx.x;
  const int swz = (bid & 7) * (nwg >> 3) + (bid >> 3);   // nwg % 8 == 0
  const int m0 = (swz / nbx) * 256, n0 = (swz % nbx) * 192;
  const int wm = wid >> 2, wn = wid & 3;
  const int nt = K / 32;

  // stage sources: granule g covers LDS bytes [g*1024, +1024), lane covers g*1024+lane*16
  // linear LDS dest; global source pre-swizzled (rule #21)
  int offA0 = wid * 1024 + lane * 16;        int sa0 = SWZ(offA0);
  int offA1 = (wid + 8) * 1024 + lane * 16;  int sa1 = SWZ(offA1);
  int offB0 = wid * 1024 + lane * 16;        int sb0 = SWZ(offB0);
  int offB1 = (wid + 8) * 1024 + lane * 16;  int sb1 = SWZ(offB1);
  const short* sAp0 = A + (size_t)(m0 + (sa0 >> 6)) * K + ((sa0 & 63) >> 1);
  const short* sAp1 = A + (size_t)(m0 + (sa1 >> 6)) * K + ((sa1 & 63) >> 1);
  const short* sBp0 = Bt + (size_t)(n0 + (sb0 >> 6)) * K + ((sb0 & 63) >> 1);
  const short* sBp1 = (wid < 4) ? (Bt + (size_t)(n0 + (sb1 >> 6)) * K + ((sb1 & 63) >> 1)) : nullptr;
  const int dA0 = wid * 1024, dA1 = (wid + 8) * 1024;
  const int dB0 = 16384 + wid * 1024, dB1 = 16384 + (wid + 8) * 1024;

  // ds_read fragment byte offsets (swizzled), fixed per lane
  int aoff[8], boff[3];
  #pragma unroll
  for (int mf = 0; mf < 8; ++mf) {
    int row = wm * 128 + mf * 16 + (lane & 15);
    int o = row * 64 + (lane >> 4) * 16;
    aoff[mf] = SWZ(o);
  }
  #pragma unroll
  for (int nf = 0; nf < 3; ++nf) {
    int row = wn * 48 + nf * 16 + (lane & 15);
    int o = row * 64 + (lane >> 4) * 16;
    boff[nf] = 16384 + SWZ(o);
  }

  f32x4 acc[8][3] = {};

  auto stage = [&](int ts, int bo) {
    int ko = ts * 32;
    gl_lds16(sAp0 + ko, ldsb + bo + dA0);
    gl_lds16(sAp1 + ko, ldsb + bo + dA1);
    gl_lds16(sBp0 + ko, ldsb + bo + dB0);
    if (wid < 4) gl_lds16(sBp1 + ko, ldsb + bo + dB1);
  };

  // prologue: tiles 0,1
  stage(0, 0);
  stage(1, 28672);
  if (wid < 4) asm volatile("s_waitcnt vmcnt(4)" ::: "memory");
  else         asm volatile("s_waitcnt vmcnt(3)" ::: "memory");
  __builtin_amdgcn_s_barrier();

  for (int tau = 0; tau < nt; ++tau) {
    const int bo = (tau & 1) * 28672;
    s8bf af[8], bfr[3];
    #pragma unroll
    for (int mf = 0; mf < 8; ++mf) af[mf] = *(const s8bf*)(ldsb + bo + aoff[mf]);
    #pragma unroll
    for (int nf = 0; nf < 3; ++nf) bfr[nf] = *(const s8bf*)(ldsb + bo + boff[nf]);
    // all waves done reading buffer (tau&1) before anyone overwrites it
    asm volatile("s_waitcnt lgkmcnt(0)" ::: "memory");
    __builtin_amdgcn_s_barrier();
    int ts = tau + 2; if (ts > nt - 1) ts = nt - 1;   // clamped dummy keeps vmcnt ledger uniform
    stage(ts, bo);
    __builtin_amdgcn_s_setprio(1);
    #pragma unroll
    for (int mf = 0; mf < 8; ++mf)
      #pragma unroll
      for (int nf = 0; nf < 3; ++nf)
        acc[mf][nf] = mfma16(af[mf], bfr[nf], acc[mf][nf]);
    __builtin_amdgcn_s_setprio(0);
    // tau+1 landed iff only tau+2's stages remain outstanding (in-order vmcnt)
    if (wid < 4) asm volatile("s_waitcnt vmcnt(4)" ::: "memory");
    else         asm volatile("s_waitcnt vmcnt(3)" ::: "memory");
    __builtin_amdgcn_s_barrier();
  }
  asm volatile("s_waitcnt vmcnt(0)" ::: "memory");  // drain dummy stages before LDS dealloc

  const int r0 = m0 + wm * 128 + ((lane >> 4) << 2);
  const int c0 = n0 + wn * 48 + (lane & 15);
  #pragma unroll
  for (int mf = 0; mf < 8; ++mf)
    #pragma unroll
    for (int nf = 0; nf < 3; ++nf)
      #pragma unroll
      for (int v = 0; v < 4; ++v) {
        int row = r0 + mf * 16 + v, col = c0 + nf * 16;
        float val = acc[mf][nf][v];
        if (MODE == 0) ((short*)C)[(size_t)row * N + col] = f2bf(val);
        else           ((float*)C)[(size_t)row * N + col] = val;
      }
}
#undef SWZ

// ---------------- m97-style GEMM kept for split-K K/V projection ----------------
// MODE 4: atomicAdd f32; cols [0,1536) -> Kf row-major, cols [1536,3072) -> Vt transposed
template<int MODE>
__global__ __launch_bounds__(256, 2) void gemm_bt_k(
    const short* __restrict__ A, const short* __restrict__ Bt, void* __restrict__ C,
    int M, int N, int K, int kchunk)
{
  __shared__ short aT[128 * 32];
  __shared__ short bT[128 * 32];
  const int m0 = blockIdx.x * 128, n0 = blockIdx.y * 128;
  const int wid = threadIdx.x >> 6, lane = threadIdx.x & 63;
  const int wr = wid >> 1, wc = wid & 1;
  const int k_lo = blockIdx.z * kchunk, k_hi = k_lo + kchunk;
  f32x4 acc[4][4] = {};
  const int srow = wid * 32 + (lane >> 2);
  const int skoff = (lane & 3) * 8;
  const short* aG = A + (size_t)(m0 + srow) * K + skoff;
  const short* bG = Bt + (size_t)(n0 + srow) * K + skoff;
  char* aL = (char*)aT + wid * 2048;
  char* bL = (char*)bT + wid * 2048;
  const short* ap = aT + (wr * 64 + (lane & 15)) * 32 + (lane >> 4) * 8;
  const short* bp = bT + (wc * 64 + (lane & 15)) * 32 + (lane >> 4) * 8;
  for (int k0 = k_lo; k0 < k_hi; k0 += 32) {
    gl_lds16(aG + k0, aL);
    gl_lds16(aG + (size_t)16 * K + k0, aL + 1024);
    gl_lds16(bG + k0, bL);
    gl_lds16(bG + (size_t)16 * K + k0, bL + 1024);
    __syncthreads();
    s8bf af[4], bf[4];
    #pragma unroll
    for (int i = 0; i < 4; ++i) {
      af[i] = *(const s8bf*)(ap + i * 512);
      bf[i] = *(const s8bf*)(bp + i * 512);
    }
    #pragma unroll
    for (int mi = 0; mi < 4; ++mi)
      #pragma unroll
      for (int ni = 0; ni < 4; ++ni)
        acc[mi][ni] = mfma16(af[mi], bf[ni], acc[mi][ni]);
    __syncthreads();
  }
  const int r0 = m0 + wr * 64 + ((lane >> 4) << 2);
  const int c0 = n0 + wc * 64 + (lane & 15);
  #pragma unroll
  for (int mi = 0; mi < 4; ++mi)
    #pragma unroll
    for (int ni = 0; ni < 4; ++ni)
      #pragma unroll
      for (int v = 0; v < 4; ++v) {
        int row = r0 + mi * 16 + v, col = c0 + ni * 16;
        float val = acc[mi][ni][v];
        if (MODE == 4) {
          if (col < 1536) atomicAdd((float*)C + ((size_t)row * 1536 + col), val);
          else { int bb = row >> 7, j = row & 127;
                 atomicAdd((float*)C + 393216 + ((size_t)(bb * 1536 + (col - 1536))) * 128 + j, val); }
        }
      }
}

// ---------------- fused attention for one (i-tile=128, head, batch) ----------------
__global__ __launch_bounds__(256, 2) void attn_k(
    const short* __restrict__ q, const short* __restrict__ kk,
    const short* __restrict__ vt, const float* __restrict__ bias,
    short* __restrict__ ao)
{
  __shared__ short kT[128 * 64];
  __shared__ short vT[64 * 128];
  __shared__ short pT[4][32 * 128];
  const int it = blockIdx.x, h = blockIdx.y, b = blockIdx.z;
  const int wid = threadIdx.x >> 6, lane = threadIdx.x & 63;
  const int i0 = it * 128;

  #pragma unroll
  for (int c = 0; c < 4; ++c) {
    int seg = c * 256 + wid * 64 + lane;
    int j = seg >> 3, ds = seg & 7;
    int dsrc = ds ^ (j & 7);
    gl_lds16(kk + ((size_t)(b * 128 + j) * 1536 + h * 64 + dsrc * 8),
             (char*)kT + c * 4096 + wid * 1024);
  }
  #pragma unroll
  for (int c = 0; c < 4; ++c) {
    int seg = c * 256 + wid * 64 + lane;
    int d = seg >> 4, js = seg & 15;
    int jsrc = js ^ (d & 7);
    gl_lds16(vt + ((size_t)(b * 1536 + h * 64 + d) * 128 + jsrc * 8),
             (char*)vT + c * 4096 + wid * 1024);
  }

  float bcol[8];
  #pragma unroll
  for (int nj = 0; nj < 8; ++nj) bcol[nj] = bias[b * 128 + nj * 16 + (lane & 15)];

  s8bf qf[2][2];
  #pragma unroll
  for (int mi = 0; mi < 2; ++mi)
    #pragma unroll
    for (int ks = 0; ks < 2; ++ks) {
      size_t row = (size_t)(b * 4096 + i0 + wid * 32 + mi * 16 + (lane & 15));
      qf[mi][ks] = *(const s8bf*)(q + row * 1536 + h * 64 + ks * 32 + (lane >> 4) * 8);
    }
  __syncthreads();

  f32x4 s[2][8] = {};
  #pragma unroll
  for (int ks = 0; ks < 2; ++ks) {
    int kd = ks * 32 + (lane >> 4) * 8;
    #pragma unroll
    for (int nj = 0; nj < 8; ++nj) {
      int j = nj * 16 + (lane & 15);
      s8bf kb = *(const s8bf*)((const char*)kT + j * 128 + ((2 * kd) ^ ((j & 7) << 4)));
      s[0][nj] = mfma16(qf[0][ks], kb, s[0][nj]);
      s[1][nj] = mfma16(qf[1][ks], kb, s[1][nj]);
    }
  }

  float sm[2][4];
  #pragma unroll
  for (int mi = 0; mi < 2; ++mi)
    #pragma unroll
    for (int v = 0; v < 4; ++v) {
      float mx = -1e30f;
      #pragma unroll
      for (int nj = 0; nj < 8; ++nj) {
        float sv = s[mi][nj][v] * 0.125f + bcol[nj];
        s[mi][nj][v] = sv;
        mx = fmaxf(mx, sv);
      }
      mx = fmaxf(mx, __shfl_xor(mx, 1));
      mx = fmaxf(mx, __shfl_xor(mx, 2));
      mx = fmaxf(mx, __shfl_xor(mx, 4));
      mx = fmaxf(mx, __shfl_xor(mx, 8));
      float ss = 0.f;
      #pragma unroll
      for (int nj = 0; nj < 8; ++nj) {
        float p = __expf(s[mi][nj][v] - mx);
        s[mi][nj][v] = p;
        ss += p;
      }
      ss += __shfl_xor(ss, 1);
      ss += __shfl_xor(ss, 2);
      ss += __shfl_xor(ss, 4);
      ss += __shfl_xor(ss, 8);
      sm[mi][v] = ss;
    }

  #pragma unroll
  for (int mi = 0; mi < 2; ++mi)
    #pragma unroll
    for (int v = 0; v < 4; ++v) {
      int r = mi * 16 + ((lane >> 4) << 2) + v;
      char* base = (char*)&pT[wid][0] + r * 256;
      #pragma unroll
      for (int nj = 0; nj < 8; ++nj) {
        int j = nj * 16 + (lane & 15);
        *(short*)(base + ((2 * j) ^ ((r & 7) << 4))) = f2bf(s[mi][nj][v]);
      }
    }
  __syncthreads();

  f32x4 o_[2][4] = {};
  #pragma unroll
  for (int ks = 0; ks < 4; ++ks) {
    int j = ks * 32 + (lane >> 4) * 8;
    s8bf pa[2];
    #pragma unroll
    for (int mi = 0; mi < 2; ++mi) {
      int r = mi * 16 + (lane & 15);
      pa[mi] = *(const s8bf*)((const char*)&pT[wid][0] + r * 256 + ((2 * j) ^ ((r & 7) << 4)));
    }
    #pragma unroll
    for (int dj = 0; dj < 4; ++dj) {
      int d = dj * 16 + (lane & 15);
      s8bf vb = *(const s8bf*)((const char*)vT + d * 256 + ((2 * j) ^ ((d & 7) << 4)));
      o_[0][dj] = mfma16(pa[0], vb, o_[0][dj]);
      o_[1][dj] = mfma16(pa[1], vb, o_[1][dj]);
    }
  }

  #pragma unroll
  for (int mi = 0; mi < 2; ++mi)
    #pragma unroll
    for (int v = 0; v < 4; ++v) {
      int r = mi * 16 + ((lane >> 4) << 2) + v;
      float is = 1.0f / sm[mi][v];
      size_t row = (size_t)(b * 4096 + i0 + wid * 32 + r);
      #pragma unroll
      for (int dj = 0; dj < 4; ++dj) {
        int d = dj * 16 + (lane & 15);
        ao[row * 1536 + h * 64 + d] = f2bf(o_[mi][dj][v] * is);
      }
    }
}

extern "C" void kernel_launch(void* const* d_in, const int* in_sizes, int n_in,
                              void* d_out, int out_size, void* d_ws, size_t ws_size,
                              hipStream_t stream) {
  const float* x   = (const float*)d_in[0];
  const float* ctx = (const float*)d_in[1];
  const void*  msk = d_in[2];
  const float* Wq  = (const float*)d_in[3];
  const float* Wk  = (const float*)d_in[4];
  const float* Wv  = (const float*)d_in[5];
  const float* Wo  = (const float*)d_in[6];
  float* out = (float*)d_out;

  const int B = 2, NI = 4096, NT = 128, C = 1536, CC = 4096, H = 24;
  const int Mq = B * NI;  // 8192
  const int Mk = B * NT;  // 256

  size_t off = 0;
  auto carve = [&](size_t bytes) -> void* {
    void* p = (char*)d_ws + off;
    off += (bytes + 255) & ~(size_t)255;
    return p;
  };
  short* xbf   = (short*)carve((size_t)Mq * C * 2);   // reused as attn-out after Q-proj
  short* ctxbf = (short*)carve((size_t)Mk * CC * 2);
  short* WqT   = (short*)carve((size_t)C * C * 2);
  short* WkT   = (short*)carve((size_t)CC * C * 2);   // WvT must follow contiguously
  short* WvT   = (short*)carve((size_t)CC * C * 2);
  short* WoT   = (short*)carve((size_t)C * C * 2);
  short* qbf   = (short*)carve((size_t)Mq * C * 2);
  float* kf    = (float*)carve((size_t)Mk * C * 4);   // vtf must follow contiguously
  float* vtf   = (float*)carve((size_t)Mk * C * 4);
  short* kbf   = (short*)carve((size_t)Mk * C * 2);   // vtbf must follow contiguously
  short* vtbf  = (short*)carve((size_t)Mk * C * 2);
  float* bias  = (float*)carve(256 * 4);
  short* aout  = xbf;  // alias: x dead after Q-proj
  (void)vtf; (void)vtbf;

  // pre-pass
  cvt_f32_bf16_k<<<(Mq * C / 4 + 255) / 256, 256, 0, stream>>>(x, xbf, Mq * C / 4);
  cvt_f32_bf16_k<<<(Mk * CC / 4 + 255) / 256, 256, 0, stream>>>(ctx, ctxbf, Mk * CC / 4);
  transp_bf16_k<<<dim3(C / 32, C / 32), 256, 0, stream>>>(Wq, WqT, C, C);
  transp_bf16_k<<<dim3(CC / 32, C / 32), 256, 0, stream>>>(Wk, WkT, CC, C);
  transp_bf16_k<<<dim3(CC / 32, C / 32), 256, 0, stream>>>(Wv, WvT, CC, C);
  transp_bf16_k<<<dim3(C / 32, C / 32), 256, 0, stream>>>(Wo, WoT, C, C);
  mask_bias_k<<<1, 256, 0, stream>>>(msk, bias, 256);
  hipMemsetAsync(kf, 0, (size_t)Mk * C * 4 * 2, stream);  // kf + vtf

  // Q projection (pipelined GEMM, bf16 out)
  gemm8p_k<0><<<(Mq / 256) * (C / 192), 512, 0, stream>>>(xbf, WqT, qbf, Mq, C, C);
  // K+V projections merged (split-K=8, atomic f32; Bt = [WkT;WvT], N=3072)
  gemm_bt_k<4><<<dim3(Mk / 128, 3072 / 128, 8), 256, 0, stream>>>(ctxbf, WkT, kf, Mk, 3072, CC, 512);
  // single cast over kf+vtf -> kbf+vtbf (contiguous)
  cvt_f32_bf16_k<<<(Mk * C * 2 / 4 + 255) / 256, 256, 0, stream>>>(kf, kbf, Mk * C * 2 / 4);

  // fused attention
  attn_k<<<dim3(NI / 128, H, B), 256, 0, stream>>>(qbf, kbf, vtbf, bias, aout);

  // output projection (pipelined GEMM, f32 out)
  gemm8p_k<1><<<(Mq / 256) * (C / 192), 512, 0, stream>>>(aout, WoT, out, Mq, C, C);
}

// Round 3
// 191.984 us; speedup vs baseline: 1.3141x; 1.2118x over previous
//
#include <hip/hip_runtime.h>

typedef __attribute__((ext_vector_type(8))) short s8bf;     // 8 bf16 payload
typedef __attribute__((ext_vector_type(8))) __bf16 v8bf;    // MFMA operand type
typedef __attribute__((ext_vector_type(4))) float f32x4;

__device__ __forceinline__ short f2bf(float f) {
  union { float f; unsigned u; } v; v.f = f;
  unsigned r = v.u + 0x7FFFu + ((v.u >> 16) & 1u);  // RNE
  return (short)(r >> 16);
}

__device__ __forceinline__ f32x4 mfma16(s8bf a, s8bf b, f32x4 c) {
  return __builtin_amdgcn_mfma_f32_16x16x32_bf16(
      __builtin_bit_cast(v8bf, a), __builtin_bit_cast(v8bf, b), c, 0, 0, 0);
}

__device__ __forceinline__ void gl_lds16(const void* g, void* l) {
  __builtin_amdgcn_global_load_lds(
      (const __attribute__((address_space(1))) unsigned*)g,
      (__attribute__((address_space(3))) unsigned*)l, 16, 0, 0);
}

// ---------------- f32 -> bf16 cast (vectorized) ----------------
__global__ void cvt_f32_bf16_k(const float* __restrict__ in, short* __restrict__ out, int n4) {
  int i = blockIdx.x * 256 + threadIdx.x;
  if (i < n4) {
    float4 v = ((const float4*)in)[i];
    short4 o;
    o.x = f2bf(v.x); o.y = f2bf(v.y); o.z = f2bf(v.z); o.w = f2bf(v.w);
    ((short4*)out)[i] = o;
  }
}

// ---------------- W [K][N] f32 -> Wt [N][K] bf16 ----------------
__global__ void transp_bf16_k(const float* __restrict__ W, short* __restrict__ Wt, int K, int N) {
  __shared__ float t[32][33];
  int k0 = blockIdx.x * 32, n0 = blockIdx.y * 32;
  int tx = threadIdx.x & 31, ty = threadIdx.x >> 5;  // ty 0..7
  #pragma unroll
  for (int i = 0; i < 4; ++i)
    t[ty + i * 8][tx] = W[(size_t)(k0 + ty + i * 8) * N + n0 + tx];
  __syncthreads();
  #pragma unroll
  for (int i = 0; i < 4; ++i)
    Wt[(size_t)(n0 + ty + i * 8) * K + k0 + tx] = f2bf(t[tx][ty + i * 8]);
}

// ---------------- mask -> additive bias, dtype-robust ----------------
__global__ void mask_bias_k(const void* __restrict__ mask, float* __restrict__ bias, int n) {
  __shared__ int fmt;  // 0=u8, 1=i32, 2=f32
  const unsigned char* p8 = (const unsigned char*)mask;
  if (threadIdx.x == 0) {
    const float* pf = (const float*)mask;
    int allf = 1, anyone = 0;
    for (int i = 0; i < 64; ++i) {
      float f = pf[i];
      if (f != 0.0f && f != 1.0f) allf = 0;
      if (f == 1.0f) anyone = 1;
    }
    int any13 = 0;
    for (int i = 0; i < 256; ++i) if ((i & 3) && p8[i]) any13 = 1;
    fmt = (allf && anyone) ? 2 : (any13 ? 0 : 1);
  }
  __syncthreads();
  int j = threadIdx.x;
  if (j < n) {
    int m;
    if (fmt == 2)      m = (((const float*)mask)[j] != 0.0f);
    else if (fmt == 0) m = (p8[j] != 0);
    else               m = (((const int*)mask)[j] != 0);
    bias[j] = m ? 0.0f : -1e30f;
  }
}

// ======== pipelined 256x192 GEMM, counted vmcnt, T2 swizzle, T5 setprio ========
// A[M][K] bf16 @ Bt[N][K]^T -> C[M][N].  MODE 0: bf16 store, 1: f32 store.
#define SWZ(o) ((o) ^ ((((o) >> 7) & 7) << 4))
template<int MODE>
__global__ __launch_bounds__(512, 2) void gemm8p_k(
    const short* __restrict__ A, const short* __restrict__ Bt, void* __restrict__ C,
    int M, int N, int K)
{
  __shared__ short lds[2 * 14336];  // per buf: A 16KB (256x32) + B 12KB (192x32)
  char* ldsb = (char*)lds;
  const int tid = threadIdx.x, wid = tid >> 6, lane = tid & 63;
  const int nbx = N / 192;
  const int nwg = gridDim.x;
  const int bid = blockIdx.x;
  const int swz = (bid & 7) * (nwg >> 3) + (bid >> 3);   // nwg % 8 == 0
  const int m0 = (swz / nbx) * 256, n0 = (swz % nbx) * 192;
  const int wm = wid >> 2, wn = wid & 3;
  const int nt = K / 32;

  int offA0 = wid * 1024 + lane * 16;        int sa0 = SWZ(offA0);
  int offA1 = (wid + 8) * 1024 + lane * 16;  int sa1 = SWZ(offA1);
  int offB0 = wid * 1024 + lane * 16;        int sb0 = SWZ(offB0);
  int offB1 = (wid + 8) * 1024 + lane * 16;  int sb1 = SWZ(offB1);
  const short* sAp0 = A + (size_t)(m0 + (sa0 >> 6)) * K + ((sa0 & 63) >> 1);
  const short* sAp1 = A + (size_t)(m0 + (sa1 >> 6)) * K + ((sa1 & 63) >> 1);
  const short* sBp0 = Bt + (size_t)(n0 + (sb0 >> 6)) * K + ((sb0 & 63) >> 1);
  const short* sBp1 = (wid < 4) ? (Bt + (size_t)(n0 + (sb1 >> 6)) * K + ((sb1 & 63) >> 1)) : nullptr;
  const int dA0 = wid * 1024, dA1 = (wid + 8) * 1024;
  const int dB0 = 16384 + wid * 1024, dB1 = 16384 + (wid + 8) * 1024;

  int aoff[8], boff[3];
  #pragma unroll
  for (int mf = 0; mf < 8; ++mf) {
    int row = wm * 128 + mf * 16 + (lane & 15);
    int o = row * 64 + (lane >> 4) * 16;
    aoff[mf] = SWZ(o);
  }
  #pragma unroll
  for (int nf = 0; nf < 3; ++nf) {
    int row = wn * 48 + nf * 16 + (lane & 15);
    int o = row * 64 + (lane >> 4) * 16;
    boff[nf] = 16384 + SWZ(o);
  }

  f32x4 acc[8][3] = {};

  auto stage = [&](int ts, int bo) {
    int ko = ts * 32;
    gl_lds16(sAp0 + ko, ldsb + bo + dA0);
    gl_lds16(sAp1 + ko, ldsb + bo + dA1);
    gl_lds16(sBp0 + ko, ldsb + bo + dB0);
    if (wid < 4) gl_lds16(sBp1 + ko, ldsb + bo + dB1);
  };

  stage(0, 0);
  stage(1, 28672);
  if (wid < 4) asm volatile("s_waitcnt vmcnt(4)" ::: "memory");
  else         asm volatile("s_waitcnt vmcnt(3)" ::: "memory");
  __builtin_amdgcn_s_barrier();

  for (int tau = 0; tau < nt; ++tau) {
    const int bo = (tau & 1) * 28672;
    s8bf af[8], bfr[3];
    #pragma unroll
    for (int mf = 0; mf < 8; ++mf) af[mf] = *(const s8bf*)(ldsb + bo + aoff[mf]);
    #pragma unroll
    for (int nf = 0; nf < 3; ++nf) bfr[nf] = *(const s8bf*)(ldsb + bo + boff[nf]);
    asm volatile("s_waitcnt lgkmcnt(0)" ::: "memory");
    __builtin_amdgcn_s_barrier();
    int ts = tau + 2; if (ts > nt - 1) ts = nt - 1;   // clamped dummy keeps vmcnt ledger uniform
    stage(ts, bo);
    __builtin_amdgcn_s_setprio(1);
    #pragma unroll
    for (int mf = 0; mf < 8; ++mf)
      #pragma unroll
      for (int nf = 0; nf < 3; ++nf)
        acc[mf][nf] = mfma16(af[mf], bfr[nf], acc[mf][nf]);
    __builtin_amdgcn_s_setprio(0);
    if (wid < 4) asm volatile("s_waitcnt vmcnt(4)" ::: "memory");
    else         asm volatile("s_waitcnt vmcnt(3)" ::: "memory");
    __builtin_amdgcn_s_barrier();
  }
  asm volatile("s_waitcnt vmcnt(0)" ::: "memory");

  const int r0 = m0 + wm * 128 + ((lane >> 4) << 2);
  const int c0 = n0 + wn * 48 + (lane & 15);
  #pragma unroll
  for (int mf = 0; mf < 8; ++mf)
    #pragma unroll
    for (int nf = 0; nf < 3; ++nf)
      #pragma unroll
      for (int v = 0; v < 4; ++v) {
        int row = r0 + mf * 16 + v, col = c0 + nf * 16;
        float val = acc[mf][nf][v];
        if (MODE == 0) ((short*)C)[(size_t)row * N + col] = f2bf(val);
        else           ((float*)C)[(size_t)row * N + col] = val;
      }
}
#undef SWZ

// ---------------- m97-style GEMM for split-K K/V projection ----------------
// MODE 5: per-slice f32 partial store (no atomics): C[z][row][col], slice stride 256*3072
template<int MODE>
__global__ __launch_bounds__(256, 2) void gemm_bt_k(
    const short* __restrict__ A, const short* __restrict__ Bt, void* __restrict__ C,
    int M, int N, int K, int kchunk)
{
  __shared__ short aT[128 * 32];
  __shared__ short bT[128 * 32];
  const int m0 = blockIdx.x * 128, n0 = blockIdx.y * 128;
  const int wid = threadIdx.x >> 6, lane = threadIdx.x & 63;
  const int wr = wid >> 1, wc = wid & 1;
  const int k_lo = blockIdx.z * kchunk, k_hi = k_lo + kchunk;
  f32x4 acc[4][4] = {};
  const int srow = wid * 32 + (lane >> 2);
  const int skoff = (lane & 3) * 8;
  const short* aG = A + (size_t)(m0 + srow) * K + skoff;
  const short* bG = Bt + (size_t)(n0 + srow) * K + skoff;
  char* aL = (char*)aT + wid * 2048;
  char* bL = (char*)bT + wid * 2048;
  const short* ap = aT + (wr * 64 + (lane & 15)) * 32 + (lane >> 4) * 8;
  const short* bp = bT + (wc * 64 + (lane & 15)) * 32 + (lane >> 4) * 8;
  for (int k0 = k_lo; k0 < k_hi; k0 += 32) {
    gl_lds16(aG + k0, aL);
    gl_lds16(aG + (size_t)16 * K + k0, aL + 1024);
    gl_lds16(bG + k0, bL);
    gl_lds16(bG + (size_t)16 * K + k0, bL + 1024);
    __syncthreads();
    s8bf af[4], bf[4];
    #pragma unroll
    for (int i = 0; i < 4; ++i) {
      af[i] = *(const s8bf*)(ap + i * 512);
      bf[i] = *(const s8bf*)(bp + i * 512);
    }
    #pragma unroll
    for (int mi = 0; mi < 4; ++mi)
      #pragma unroll
      for (int ni = 0; ni < 4; ++ni)
        acc[mi][ni] = mfma16(af[mi], bf[ni], acc[mi][ni]);
    __syncthreads();
  }
  const int r0 = m0 + wr * 64 + ((lane >> 4) << 2);
  const int c0 = n0 + wc * 64 + (lane & 15);
  float* Cf = (float*)C + (size_t)blockIdx.z * 786432;
  #pragma unroll
  for (int mi = 0; mi < 4; ++mi)
    #pragma unroll
    for (int ni = 0; ni < 4; ++ni)
      #pragma unroll
      for (int v = 0; v < 4; ++v) {
        int row = r0 + mi * 16 + v, col = c0 + ni * 16;
        Cf[(size_t)row * N + col] = acc[mi][ni][v];
      }
}

// ---------------- reduce 4 split-K slices -> bf16 K (row-major) + V^T ----------------
__global__ void kv_reduce_k(const float* __restrict__ part, short* __restrict__ kbf,
                            short* __restrict__ vtbf) {
  int t = blockIdx.x * 256 + threadIdx.x;          // t < 196608
  int row = t / 768, c4 = (t % 768) * 4;
  float4 s = {0.f, 0.f, 0.f, 0.f};
  const float* p = part + (size_t)row * 3072 + c4;
  #pragma unroll
  for (int z = 0; z < 4; ++z) {
    float4 v = *(const float4*)(p + (size_t)z * 786432);
    s.x += v.x; s.y += v.y; s.z += v.z; s.w += v.w;
  }
  if (c4 < 1536) {
    short4 o = { f2bf(s.x), f2bf(s.y), f2bf(s.z), f2bf(s.w) };
    *(short4*)(kbf + (size_t)row * 1536 + c4) = o;
  } else {
    int b = row >> 7, j = row & 127, c = c4 - 1536;
    vtbf[((size_t)(b * 1536 + c + 0)) * 128 + j] = f2bf(s.x);
    vtbf[((size_t)(b * 1536 + c + 1)) * 128 + j] = f2bf(s.y);
    vtbf[((size_t)(b * 1536 + c + 2)) * 128 + j] = f2bf(s.z);
    vtbf[((size_t)(b * 1536 + c + 3)) * 128 + j] = f2bf(s.w);
  }
}

// ---------------- fused attention for one (i-tile=128, head, batch) ----------------
// LDS 48KB: kT [0,16K), vT [16K,32K), P: waves 0/1 alias dead kT, waves 2/3 at [32K,48K)
__global__ __launch_bounds__(256, 3) void attn_k(
    const short* __restrict__ q, const short* __restrict__ kk,
    const short* __restrict__ vt, const float* __restrict__ bias,
    short* __restrict__ ao)
{
  __shared__ char sm_[49152];
  const int it = blockIdx.x, h = blockIdx.y, b = blockIdx.z;
  const int wid = threadIdx.x >> 6, lane = threadIdx.x & 63;
  const int i0 = it * 128;
  char* kT = sm_;
  char* vT = sm_ + 16384;
  char* pB = (wid < 2) ? (sm_ + wid * 8192) : (sm_ + 16384 + wid * 8192);

  #pragma unroll
  for (int c = 0; c < 4; ++c) {
    int seg = c * 256 + wid * 64 + lane;
    int j = seg >> 3, ds = seg & 7;
    int dsrc = ds ^ (j & 7);
    gl_lds16(kk + ((size_t)(b * 128 + j) * 1536 + h * 64 + dsrc * 8),
             kT + c * 4096 + wid * 1024);
  }
  #pragma unroll
  for (int c = 0; c < 4; ++c) {
    int seg = c * 256 + wid * 64 + lane;
    int d = seg >> 4, js = seg & 15;
    int jsrc = js ^ (d & 7);
    gl_lds16(vt + ((size_t)(b * 1536 + h * 64 + d) * 128 + jsrc * 8),
             vT + c * 4096 + wid * 1024);
  }

  float bcol[8];
  #pragma unroll
  for (int nj = 0; nj < 8; ++nj) bcol[nj] = bias[b * 128 + nj * 16 + (lane & 15)];

  s8bf qf[2][2];
  #pragma unroll
  for (int mi = 0; mi < 2; ++mi)
    #pragma unroll
    for (int ks = 0; ks < 2; ++ks) {
      size_t row = (size_t)(b * 4096 + i0 + wid * 32 + mi * 16 + (lane & 15));
      qf[mi][ks] = *(const s8bf*)(q + row * 1536 + h * 64 + ks * 32 + (lane >> 4) * 8);
    }
  __syncthreads();

  f32x4 s[2][8] = {};
  #pragma unroll
  for (int ks = 0; ks < 2; ++ks) {
    int kd = ks * 32 + (lane >> 4) * 8;
    #pragma unroll
    for (int nj = 0; nj < 8; ++nj) {
      int j = nj * 16 + (lane & 15);
      s8bf kb = *(const s8bf*)(kT + j * 128 + ((2 * kd) ^ ((j & 7) << 4)));
      s[0][nj] = mfma16(qf[0][ks], kb, s[0][nj]);
      s[1][nj] = mfma16(qf[1][ks], kb, s[1][nj]);
    }
  }
  __syncthreads();   // kT handoff: all waves done with K before P overlays it

  float sm[2][4];
  #pragma unroll
  for (int mi = 0; mi < 2; ++mi)
    #pragma unroll
    for (int v = 0; v < 4; ++v) {
      float mx = -1e30f;
      #pragma unroll
      for (int nj = 0; nj < 8; ++nj) {
        float sv = s[mi][nj][v] * 0.125f + bcol[nj];
        s[mi][nj][v] = sv;
        mx = fmaxf(mx, sv);
      }
      mx = fmaxf(mx, __shfl_xor(mx, 1));
      mx = fmaxf(mx, __shfl_xor(mx, 2));
      mx = fmaxf(mx, __shfl_xor(mx, 4));
      mx = fmaxf(mx, __shfl_xor(mx, 8));
      float ss = 0.f;
      #pragma unroll
      for (int nj = 0; nj < 8; ++nj) {
        float p = __expf(s[mi][nj][v] - mx);
        s[mi][nj][v] = p;
        ss += p;
      }
      ss += __shfl_xor(ss, 1);
      ss += __shfl_xor(ss, 2);
      ss += __shfl_xor(ss, 4);
      ss += __shfl_xor(ss, 8);
      sm[mi][v] = ss;
    }

  #pragma unroll
  for (int mi = 0; mi < 2; ++mi)
    #pragma unroll
    for (int v = 0; v < 4; ++v) {
      int r = mi * 16 + ((lane >> 4) << 2) + v;
      char* base = pB + r * 256;
      #pragma unroll
      for (int nj = 0; nj < 8; ++nj) {
        int j = nj * 16 + (lane & 15);
        *(short*)(base + ((2 * j) ^ ((r & 7) << 4))) = f2bf(s[mi][nj][v]);
      }
    }
  __syncthreads();

  f32x4 o_[2][4] = {};
  #pragma unroll
  for (int ks = 0; ks < 4; ++ks) {
    int j = ks * 32 + (lane >> 4) * 8;
    s8bf pa[2];
    #pragma unroll
    for (int mi = 0; mi < 2; ++mi) {
      int r = mi * 16 + (lane & 15);
      pa[mi] = *(const s8bf*)(pB + r * 256 + ((2 * j) ^ ((r & 7) << 4)));
    }
    #pragma unroll
    for (int dj = 0; dj < 4; ++dj) {
      int d = dj * 16 + (lane & 15);
      s8bf vb = *(const s8bf*)(vT + d * 256 + ((2 * j) ^ ((d & 7) << 4)));
      o_[0][dj] = mfma16(pa[0], vb, o_[0][dj]);
      o_[1][dj] = mfma16(pa[1], vb, o_[1][dj]);
    }
  }

  #pragma unroll
  for (int mi = 0; mi < 2; ++mi)
    #pragma unroll
    for (int v = 0; v < 4; ++v) {
      int r = mi * 16 + ((lane >> 4) << 2) + v;
      float is = 1.0f / sm[mi][v];
      size_t row = (size_t)(b * 4096 + i0 + wid * 32 + r);
      #pragma unroll
      for (int dj = 0; dj < 4; ++dj) {
        int d = dj * 16 + (lane & 15);
        ao[row * 1536 + h * 64 + d] = f2bf(o_[mi][dj][v] * is);
      }
    }
}

extern "C" void kernel_launch(void* const* d_in, const int* in_sizes, int n_in,
                              void* d_out, int out_size, void* d_ws, size_t ws_size,
                              hipStream_t stream) {
  const float* x   = (const float*)d_in[0];
  const float* ctx = (const float*)d_in[1];
  const void*  msk = d_in[2];
  const float* Wq  = (const float*)d_in[3];
  const float* Wk  = (const float*)d_in[4];
  const float* Wv  = (const float*)d_in[5];
  const float* Wo  = (const float*)d_in[6];
  float* out = (float*)d_out;

  const int B = 2, NI = 4096, NT = 128, C = 1536, CC = 4096, H = 24;
  const int Mq = B * NI;  // 8192
  const int Mk = B * NT;  // 256

  size_t off = 0;
  auto carve = [&](size_t bytes) -> void* {
    void* p = (char*)d_ws + off;
    off += (bytes + 255) & ~(size_t)255;
    return p;
  };
  short* xbf   = (short*)carve((size_t)Mq * C * 2);   // reused as attn-out after Q-proj
  short* ctxbf = (short*)carve((size_t)Mk * CC * 2);
  short* WqT   = (short*)carve((size_t)C * C * 2);
  short* WkT   = (short*)carve((size_t)CC * C * 2);   // WvT must follow contiguously
  short* WvT   = (short*)carve((size_t)CC * C * 2);
  short* WoT   = (short*)carve((size_t)C * C * 2);
  short* qbf   = (short*)carve((size_t)Mq * C * 2);
  short* kbf   = (short*)carve((size_t)Mk * C * 2);
  short* vtbf  = (short*)carve((size_t)Mk * C * 2);
  float* bias  = (float*)carve(256 * 4);
  short* aout  = xbf;            // alias: x dead after Q-proj
  float* part  = out;            // d_out as split-K scratch (4*256*3072*4B = 12.6MB <= 50MB,
                                 // fully overwritten by final O-proj -> deterministic)

  // pre-pass
  cvt_f32_bf16_k<<<(Mq * C / 4 + 255) / 256, 256, 0, stream>>>(x, xbf, Mq * C / 4);
  cvt_f32_bf16_k<<<(Mk * CC / 4 + 255) / 256, 256, 0, stream>>>(ctx, ctxbf, Mk * CC / 4);
  transp_bf16_k<<<dim3(C / 32, C / 32), 256, 0, stream>>>(Wq, WqT, C, C);
  transp_bf16_k<<<dim3(CC / 32, C / 32), 256, 0, stream>>>(Wk, WkT, CC, C);
  transp_bf16_k<<<dim3(CC / 32, C / 32), 256, 0, stream>>>(Wv, WvT, CC, C);
  transp_bf16_k<<<dim3(C / 32, C / 32), 256, 0, stream>>>(Wo, WoT, C, C);
  mask_bias_k<<<1, 256, 0, stream>>>(msk, bias, 256);

  // Q projection (pipelined GEMM, bf16 out)
  gemm8p_k<0><<<(Mq / 256) * (C / 192), 512, 0, stream>>>(xbf, WqT, qbf, Mq, C, C);
  // K+V projections merged: split-K=4 f32 partials into d_out scratch, then reduce
  gemm_bt_k<5><<<dim3(Mk / 128, 3072 / 128, 4), 256, 0, stream>>>(ctxbf, WkT, part, Mk, 3072, CC, 1024);
  kv_reduce_k<<<768, 256, 0, stream>>>(part, kbf, vtbf);

  // fused attention
  attn_k<<<dim3(NI / 128, H, B), 256, 0, stream>>>(qbf, kbf, vtbf, bias, aout);

  // output projection (pipelined GEMM, f32 out)
  gemm8p_k<1><<<(Mq / 256) * (C / 192), 512, 0, stream>>>(aout, WoT, out, Mq, C, C);
}

// Round 4
// 187.233 us; speedup vs baseline: 1.3474x; 1.0254x over previous
//
#include <hip/hip_runtime.h>

typedef __attribute__((ext_vector_type(8))) short s8bf;     // 8 bf16 payload
typedef __attribute__((ext_vector_type(8))) __bf16 v8bf;    // MFMA operand type
typedef __attribute__((ext_vector_type(4))) float f32x4;

__device__ __forceinline__ short f2bf(float f) {
  union { float f; unsigned u; } v; v.f = f;
  unsigned r = v.u + 0x7FFFu + ((v.u >> 16) & 1u);  // RNE
  return (short)(r >> 16);
}

__device__ __forceinline__ f32x4 mfma16(s8bf a, s8bf b, f32x4 c) {
  return __builtin_amdgcn_mfma_f32_16x16x32_bf16(
      __builtin_bit_cast(v8bf, a), __builtin_bit_cast(v8bf, b), c, 0, 0, 0);
}

__device__ __forceinline__ void gl_lds16(const void* g, void* l) {
  __builtin_amdgcn_global_load_lds(
      (const __attribute__((address_space(1))) unsigned*)g,
      (__attribute__((address_space(3))) unsigned*)l, 16, 0, 0);
}

// ---------------- f32 -> bf16 cast (vectorized) ----------------
__global__ void cvt_f32_bf16_k(const float* __restrict__ in, short* __restrict__ out, int n4) {
  int i = blockIdx.x * 256 + threadIdx.x;
  if (i < n4) {
    float4 v = ((const float4*)in)[i];
    short4 o;
    o.x = f2bf(v.x); o.y = f2bf(v.y); o.z = f2bf(v.z); o.w = f2bf(v.w);
    ((short4*)out)[i] = o;
  }
}

// ---------------- W [K][N] f32 -> Wt [N][K] bf16 ----------------
__global__ void transp_bf16_k(const float* __restrict__ W, short* __restrict__ Wt, int K, int N) {
  __shared__ float t[32][33];
  int k0 = blockIdx.x * 32, n0 = blockIdx.y * 32;
  int tx = threadIdx.x & 31, ty = threadIdx.x >> 5;  // ty 0..7
  #pragma unroll
  for (int i = 0; i < 4; ++i)
    t[ty + i * 8][tx] = W[(size_t)(k0 + ty + i * 8) * N + n0 + tx];
  __syncthreads();
  #pragma unroll
  for (int i = 0; i < 4; ++i)
    Wt[(size_t)(n0 + ty + i * 8) * K + k0 + tx] = f2bf(t[tx][ty + i * 8]);
}

// ---------------- mask -> additive bias, dtype-robust ----------------
__global__ void mask_bias_k(const void* __restrict__ mask, float* __restrict__ bias, int n) {
  __shared__ int fmt;  // 0=u8, 1=i32, 2=f32
  const unsigned char* p8 = (const unsigned char*)mask;
  if (threadIdx.x == 0) {
    const float* pf = (const float*)mask;
    int allf = 1, anyone = 0;
    for (int i = 0; i < 64; ++i) {
      float f = pf[i];
      if (f != 0.0f && f != 1.0f) allf = 0;
      if (f == 1.0f) anyone = 1;
    }
    int any13 = 0;
    for (int i = 0; i < 256; ++i) if ((i & 3) && p8[i]) any13 = 1;
    fmt = (allf && anyone) ? 2 : (any13 ? 0 : 1);
  }
  __syncthreads();
  int j = threadIdx.x;
  if (j < n) {
    int m;
    if (fmt == 2)      m = (((const float*)mask)[j] != 0.0f);
    else if (fmt == 0) m = (p8[j] != 0);
    else               m = (((const int*)mask)[j] != 0);
    bias[j] = m ? 0.0f : -1e30f;
  }
}

// ======== 4-phase-per-K-tile pipelined GEMM (m201-style), BM=256 BN=192 BK=64 ========
// A[M][K] bf16 @ Bt[N][K]^T -> C[M][N].  MODE 0: bf16 store, 1: f32 store.
// Dynamic LDS 112KB: per buf A[256][64] @0 (32KB), B[192][64] @32768 (24KB); bufs at 0/57344.
// Swizzle (involution, bits4-6 ^= bits7-9 within 1KB): phys = log ^ (((log>>7)&7)<<4).
// Stage: 7 chunks x 8KB per tile, linear dest, pre-swizzled global source (rule #21).
// Ledger: boundary vmcnt(7) => tile t+1 landed (t+2's 7 in flight). ph1-end lgkmcnt(0)
// => all reads of live buffer done before ph2/ph3 stage t+2 into it (WAR-safe).
template<int MODE>
__global__ __launch_bounds__(512, 2) void gemm8ph_k(
    const short* __restrict__ A, const short* __restrict__ Bt, void* __restrict__ C,
    int M, int N, int K)
{
  extern __shared__ char ldsb[];
  const int tid = threadIdx.x, wid = tid >> 6, lane = tid & 63;
  const int nbx = N / 192;
  const int nwg = gridDim.x, bid = blockIdx.x;
  const int swz = (bid & 7) * (nwg >> 3) + (bid >> 3);   // nwg % 8 == 0
  const int m0 = (swz / nbx) * 256, n0 = (swz % nbx) * 192;
  const int wm = wid >> 2, wn = wid & 3;
  const int NT = K / 64;

  // ds_read swizzled offsets: row&7 == lane&7 for every fragment row
  const int sx  = (lane & 7) << 4;
  const int c0b = ((lane >> 4) * 16) ^ sx;          // ks=0 column bytes
  const int c1b = ((lane >> 4) * 16 + 64) ^ sx;     // ks=1
  const int aoff0 = (wm * 128 + (lane & 15)) * 128 + c0b;
  const int aoff1 = (wm * 128 + (lane & 15)) * 128 + c1b;
  const int boff0 = 32768 + (wn * 48 + (lane & 15)) * 128 + c0b;
  const int boff1 = 32768 + (wn * 48 + (lane & 15)) * 128 + c1b;

  // stage source pointers: chunk r covers physical [r*8192, +8192); thread t at +t*16
  // logical = physical ^ (((phys>>7)&7)<<4); row = r*64 + (t>>3), colb = 16*((t&7)^((t>>3)&7))
  const int strow = tid >> 3;
  const int stcol = (16 * ((tid & 7) ^ ((tid >> 3) & 7))) >> 1;  // shorts
  const short* sp[7];
  #pragma unroll
  for (int r = 0; r < 7; ++r) {
    if (r < 4) sp[r] = A  + (size_t)(m0 + r * 64 + strow) * K + stcol;
    else       sp[r] = Bt + (size_t)(n0 + (r - 4) * 64 + strow) * K + stcol;
  }

  f32x4 acc[8][3] = {};
  s8bf bfr[3][2];

  // prologue: stage tiles 0,1
  #pragma unroll
  for (int r = 0; r < 7; ++r) gl_lds16(sp[r], ldsb + r * 8192 + tid * 16);
  #pragma unroll
  for (int r = 0; r < 7; ++r) gl_lds16(sp[r] + 64, ldsb + 57344 + r * 8192 + tid * 16);
  asm volatile("s_waitcnt vmcnt(7)" ::: "memory");
  __builtin_amdgcn_s_barrier();

  for (int t = 0; t < NT; ++t) {
    const int bo = (t & 1) * 57344;
    const int so2 = ((t + 2) < NT ? (t + 2) : (NT - 1)) * 64;   // clamped dummy at tail
    s8bf a0[4], a1[4], a2[4], a3[4];
    // ---- phase 0: issue 14 ds_reads (ph0's 7 first, ph1's 7 behind)
    #pragma unroll
    for (int i = 0; i < 4; ++i) a0[i] = *(const s8bf*)(ldsb + bo + aoff0 + i * 2048);
    #pragma unroll
    for (int nf = 0; nf < 3; ++nf) bfr[nf][0] = *(const s8bf*)(ldsb + bo + boff0 + nf * 2048);
    #pragma unroll
    for (int i = 0; i < 4; ++i) a1[i] = *(const s8bf*)(ldsb + bo + aoff1 + i * 2048);
    #pragma unroll
    for (int nf = 0; nf < 3; ++nf) bfr[nf][1] = *(const s8bf*)(ldsb + bo + boff1 + nf * 2048);
    __builtin_amdgcn_s_barrier();
    asm volatile("s_waitcnt lgkmcnt(7)" ::: "memory");
    __builtin_amdgcn_s_setprio(1);
    #pragma unroll
    for (int i = 0; i < 4; ++i)
      #pragma unroll
      for (int nf = 0; nf < 3; ++nf)
        acc[i][nf] = mfma16(a0[i], bfr[nf][0], acc[i][nf]);
    __builtin_amdgcn_s_setprio(0);
    __builtin_amdgcn_s_barrier();
    // ---- phase 1: issue 8 ds_reads (af4-7 both k-slices)
    #pragma unroll
    for (int i = 0; i < 4; ++i) a2[i] = *(const s8bf*)(ldsb + bo + aoff0 + (4 + i) * 2048);
    #pragma unroll
    for (int i = 0; i < 4; ++i) a3[i] = *(const s8bf*)(ldsb + bo + aoff1 + (4 + i) * 2048);
    __builtin_amdgcn_s_barrier();
    asm volatile("s_waitcnt lgkmcnt(8)" ::: "memory");
    __builtin_amdgcn_s_setprio(1);
    #pragma unroll
    for (int i = 0; i < 4; ++i)
      #pragma unroll
      for (int nf = 0; nf < 3; ++nf)
        acc[i][nf] = mfma16(a1[i], bfr[nf][1], acc[i][nf]);
    __builtin_amdgcn_s_setprio(0);
    asm volatile("s_waitcnt lgkmcnt(0)" ::: "memory");   // all reads of live buffer done
    __builtin_amdgcn_s_barrier();
    // ---- phase 2: stage chunks 0-3 of tile t+2 into the just-drained buffer
    #pragma unroll
    for (int r = 0; r < 4; ++r) gl_lds16(sp[r] + so2, ldsb + bo + r * 8192 + tid * 16);
    __builtin_amdgcn_s_barrier();
    __builtin_amdgcn_s_setprio(1);
    #pragma unroll
    for (int i = 0; i < 4; ++i)
      #pragma unroll
      for (int nf = 0; nf < 3; ++nf)
        acc[4 + i][nf] = mfma16(a2[i], bfr[nf][0], acc[4 + i][nf]);
    __builtin_amdgcn_s_setprio(0);
    __builtin_amdgcn_s_barrier();
    // ---- phase 3: stage chunks 4-6
    #pragma unroll
    for (int r = 4; r < 7; ++r) gl_lds16(sp[r] + so2, ldsb + bo + r * 8192 + tid * 16);
    __builtin_amdgcn_s_barrier();
    __builtin_amdgcn_s_setprio(1);
    #pragma unroll
    for (int i = 0; i < 4; ++i)
      #pragma unroll
      for (int nf = 0; nf < 3; ++nf)
        acc[4 + i][nf] = mfma16(a3[i], bfr[nf][1], acc[4 + i][nf]);
    __builtin_amdgcn_s_setprio(0);
    asm volatile("s_waitcnt vmcnt(7)" ::: "memory");     // t+1 landed, t+2's 7 in flight
    __builtin_amdgcn_s_barrier();
  }
  asm volatile("s_waitcnt vmcnt(0)" ::: "memory");

  const int r0 = m0 + wm * 128 + ((lane >> 4) << 2);
  const int c0 = n0 + wn * 48 + (lane & 15);
  #pragma unroll
  for (int mf = 0; mf < 8; ++mf)
    #pragma unroll
    for (int nf = 0; nf < 3; ++nf)
      #pragma unroll
      for (int v = 0; v < 4; ++v) {
        int row = r0 + mf * 16 + v, col = c0 + nf * 16;
        float val = acc[mf][nf][v];
        if (MODE == 0) ((short*)C)[(size_t)row * N + col] = f2bf(val);
        else           ((float*)C)[(size_t)row * N + col] = val;
      }
}

// ---------------- m97-style GEMM for split-K K/V projection ----------------
// MODE 5: per-slice f32 partial store (no atomics): C[z][row][col], slice stride 256*3072
template<int MODE>
__global__ __launch_bounds__(256, 2) void gemm_bt_k(
    const short* __restrict__ A, const short* __restrict__ Bt, void* __restrict__ C,
    int M, int N, int K, int kchunk)
{
  __shared__ short aT[128 * 32];
  __shared__ short bT[128 * 32];
  const int m0 = blockIdx.x * 128, n0 = blockIdx.y * 128;
  const int wid = threadIdx.x >> 6, lane = threadIdx.x & 63;
  const int wr = wid >> 1, wc = wid & 1;
  const int k_lo = blockIdx.z * kchunk, k_hi = k_lo + kchunk;
  f32x4 acc[4][4] = {};
  const int srow = wid * 32 + (lane >> 2);
  const int skoff = (lane & 3) * 8;
  const short* aG = A + (size_t)(m0 + srow) * K + skoff;
  const short* bG = Bt + (size_t)(n0 + srow) * K + skoff;
  char* aL = (char*)aT + wid * 2048;
  char* bL = (char*)bT + wid * 2048;
  const short* ap = aT + (wr * 64 + (lane & 15)) * 32 + (lane >> 4) * 8;
  const short* bp = bT + (wc * 64 + (lane & 15)) * 32 + (lane >> 4) * 8;
  for (int k0 = k_lo; k0 < k_hi; k0 += 32) {
    gl_lds16(aG + k0, aL);
    gl_lds16(aG + (size_t)16 * K + k0, aL + 1024);
    gl_lds16(bG + k0, bL);
    gl_lds16(bG + (size_t)16 * K + k0, bL + 1024);
    __syncthreads();
    s8bf af[4], bf[4];
    #pragma unroll
    for (int i = 0; i < 4; ++i) {
      af[i] = *(const s8bf*)(ap + i * 512);
      bf[i] = *(const s8bf*)(bp + i * 512);
    }
    #pragma unroll
    for (int mi = 0; mi < 4; ++mi)
      #pragma unroll
      for (int ni = 0; ni < 4; ++ni)
        acc[mi][ni] = mfma16(af[mi], bf[ni], acc[mi][ni]);
    __syncthreads();
  }
  const int r0 = m0 + wr * 64 + ((lane >> 4) << 2);
  const int c0 = n0 + wc * 64 + (lane & 15);
  float* Cf = (float*)C + (size_t)blockIdx.z * 786432;
  #pragma unroll
  for (int mi = 0; mi < 4; ++mi)
    #pragma unroll
    for (int ni = 0; ni < 4; ++ni)
      #pragma unroll
      for (int v = 0; v < 4; ++v) {
        int row = r0 + mi * 16 + v, col = c0 + ni * 16;
        Cf[(size_t)row * N + col] = acc[mi][ni][v];
      }
}

// ---------------- reduce 4 split-K slices -> bf16 K (row-major) + V^T ----------------
__global__ void kv_reduce_k(const float* __restrict__ part, short* __restrict__ kbf,
                            short* __restrict__ vtbf) {
  int t = blockIdx.x * 256 + threadIdx.x;          // t < 196608
  int row = t / 768, c4 = (t % 768) * 4;
  float4 s = {0.f, 0.f, 0.f, 0.f};
  const float* p = part + (size_t)row * 3072 + c4;
  #pragma unroll
  for (int z = 0; z < 4; ++z) {
    float4 v = *(const float4*)(p + (size_t)z * 786432);
    s.x += v.x; s.y += v.y; s.z += v.z; s.w += v.w;
  }
  if (c4 < 1536) {
    short4 o = { f2bf(s.x), f2bf(s.y), f2bf(s.z), f2bf(s.w) };
    *(short4*)(kbf + (size_t)row * 1536 + c4) = o;
  } else {
    int b = row >> 7, j = row & 127, c = c4 - 1536;
    vtbf[((size_t)(b * 1536 + c + 0)) * 128 + j] = f2bf(s.x);
    vtbf[((size_t)(b * 1536 + c + 1)) * 128 + j] = f2bf(s.y);
    vtbf[((size_t)(b * 1536 + c + 2)) * 128 + j] = f2bf(s.z);
    vtbf[((size_t)(b * 1536 + c + 3)) * 128 + j] = f2bf(s.w);
  }
}

// ---------------- fused attention for one (i-tile=128, head, batch) ----------------
// LDS 48KB: kT [0,16K), vT [16K,32K), P: waves 0/1 alias dead kT, waves 2/3 at [32K,48K)
__global__ __launch_bounds__(256, 3) void attn_k(
    const short* __restrict__ q, const short* __restrict__ kk,
    const short* __restrict__ vt, const float* __restrict__ bias,
    short* __restrict__ ao)
{
  __shared__ char sm_[49152];
  const int it = blockIdx.x, h = blockIdx.y, b = blockIdx.z;
  const int wid = threadIdx.x >> 6, lane = threadIdx.x & 63;
  const int i0 = it * 128;
  char* kT = sm_;
  char* vT = sm_ + 16384;
  char* pB = (wid < 2) ? (sm_ + wid * 8192) : (sm_ + 16384 + wid * 8192);

  #pragma unroll
  for (int c = 0; c < 4; ++c) {
    int seg = c * 256 + wid * 64 + lane;
    int j = seg >> 3, ds = seg & 7;
    int dsrc = ds ^ (j & 7);
    gl_lds16(kk + ((size_t)(b * 128 + j) * 1536 + h * 64 + dsrc * 8),
             kT + c * 4096 + wid * 1024);
  }
  #pragma unroll
  for (int c = 0; c < 4; ++c) {
    int seg = c * 256 + wid * 64 + lane;
    int d = seg >> 4, js = seg & 15;
    int jsrc = js ^ (d & 7);
    gl_lds16(vt + ((size_t)(b * 1536 + h * 64 + d) * 128 + jsrc * 8),
             vT + c * 4096 + wid * 1024);
  }

  float bcol[8];
  #pragma unroll
  for (int nj = 0; nj < 8; ++nj) bcol[nj] = bias[b * 128 + nj * 16 + (lane & 15)];

  s8bf qf[2][2];
  #pragma unroll
  for (int mi = 0; mi < 2; ++mi)
    #pragma unroll
    for (int ks = 0; ks < 2; ++ks) {
      size_t row = (size_t)(b * 4096 + i0 + wid * 32 + mi * 16 + (lane & 15));
      qf[mi][ks] = *(const s8bf*)(q + row * 1536 + h * 64 + ks * 32 + (lane >> 4) * 8);
    }
  __syncthreads();

  f32x4 s[2][8] = {};
  #pragma unroll
  for (int ks = 0; ks < 2; ++ks) {
    int kd = ks * 32 + (lane >> 4) * 8;
    #pragma unroll
    for (int nj = 0; nj < 8; ++nj) {
      int j = nj * 16 + (lane & 15);
      s8bf kb = *(const s8bf*)(kT + j * 128 + ((2 * kd) ^ ((j & 7) << 4)));
      s[0][nj] = mfma16(qf[0][ks], kb, s[0][nj]);
      s[1][nj] = mfma16(qf[1][ks], kb, s[1][nj]);
    }
  }
  __syncthreads();   // kT handoff: all waves done with K before P overlays it

  float sm[2][4];
  #pragma unroll
  for (int mi = 0; mi < 2; ++mi)
    #pragma unroll
    for (int v = 0; v < 4; ++v) {
      float mx = -1e30f;
      #pragma unroll
      for (int nj = 0; nj < 8; ++nj) {
        float sv = s[mi][nj][v] * 0.125f + bcol[nj];
        s[mi][nj][v] = sv;
        mx = fmaxf(mx, sv);
      }
      mx = fmaxf(mx, __shfl_xor(mx, 1));
      mx = fmaxf(mx, __shfl_xor(mx, 2));
      mx = fmaxf(mx, __shfl_xor(mx, 4));
      mx = fmaxf(mx, __shfl_xor(mx, 8));
      float ss = 0.f;
      #pragma unroll
      for (int nj = 0; nj < 8; ++nj) {
        float p = __expf(s[mi][nj][v] - mx);
        s[mi][nj][v] = p;
        ss += p;
      }
      ss += __shfl_xor(ss, 1);
      ss += __shfl_xor(ss, 2);
      ss += __shfl_xor(ss, 4);
      ss += __shfl_xor(ss, 8);
      sm[mi][v] = ss;
    }

  #pragma unroll
  for (int mi = 0; mi < 2; ++mi)
    #pragma unroll
    for (int v = 0; v < 4; ++v) {
      int r = mi * 16 + ((lane >> 4) << 2) + v;
      char* base = pB + r * 256;
      #pragma unroll
      for (int nj = 0; nj < 8; ++nj) {
        int j = nj * 16 + (lane & 15);
        *(short*)(base + ((2 * j) ^ ((r & 7) << 4))) = f2bf(s[mi][nj][v]);
      }
    }
  __syncthreads();

  f32x4 o_[2][4] = {};
  #pragma unroll
  for (int ks = 0; ks < 4; ++ks) {
    int j = ks * 32 + (lane >> 4) * 8;
    s8bf pa[2];
    #pragma unroll
    for (int mi = 0; mi < 2; ++mi) {
      int r = mi * 16 + (lane & 15);
      pa[mi] = *(const s8bf*)(pB + r * 256 + ((2 * j) ^ ((r & 7) << 4)));
    }
    #pragma unroll
    for (int dj = 0; dj < 4; ++dj) {
      int d = dj * 16 + (lane & 15);
      s8bf vb = *(const s8bf*)(vT + d * 256 + ((2 * j) ^ ((d & 7) << 4)));
      o_[0][dj] = mfma16(pa[0], vb, o_[0][dj]);
      o_[1][dj] = mfma16(pa[1], vb, o_[1][dj]);
    }
  }

  #pragma unroll
  for (int mi = 0; mi < 2; ++mi)
    #pragma unroll
    for (int v = 0; v < 4; ++v) {
      int r = mi * 16 + ((lane >> 4) << 2) + v;
      float is = 1.0f / sm[mi][v];
      size_t row = (size_t)(b * 4096 + i0 + wid * 32 + r);
      #pragma unroll
      for (int dj = 0; dj < 4; ++dj) {
        int d = dj * 16 + (lane & 15);
        ao[row * 1536 + h * 64 + d] = f2bf(o_[mi][dj][v] * is);
      }
    }
}

extern "C" void kernel_launch(void* const* d_in, const int* in_sizes, int n_in,
                              void* d_out, int out_size, void* d_ws, size_t ws_size,
                              hipStream_t stream) {
  const float* x   = (const float*)d_in[0];
  const float* ctx = (const float*)d_in[1];
  const void*  msk = d_in[2];
  const float* Wq  = (const float*)d_in[3];
  const float* Wk  = (const float*)d_in[4];
  const float* Wv  = (const float*)d_in[5];
  const float* Wo  = (const float*)d_in[6];
  float* out = (float*)d_out;

  const int B = 2, NI = 4096, NT = 128, C = 1536, CC = 4096, H = 24;
  const int Mq = B * NI;  // 8192
  const int Mk = B * NT;  // 256

  size_t off = 0;
  auto carve = [&](size_t bytes) -> void* {
    void* p = (char*)d_ws + off;
    off += (bytes + 255) & ~(size_t)255;
    return p;
  };
  short* xbf   = (short*)carve((size_t)Mq * C * 2);   // reused as attn-out after Q-proj
  short* ctxbf = (short*)carve((size_t)Mk * CC * 2);
  short* WqT   = (short*)carve((size_t)C * C * 2);
  short* WkT   = (short*)carve((size_t)CC * C * 2);   // WvT must follow contiguously
  short* WvT   = (short*)carve((size_t)CC * C * 2);
  short* WoT   = (short*)carve((size_t)C * C * 2);
  short* qbf   = (short*)carve((size_t)Mq * C * 2);
  short* kbf   = (short*)carve((size_t)Mk * C * 2);
  short* vtbf  = (short*)carve((size_t)Mk * C * 2);
  float* bias  = (float*)carve(256 * 4);
  short* aout  = xbf;            // alias: x dead after Q-proj
  float* part  = out;            // d_out as split-K scratch (12.6MB, fully overwritten later)

  // allow 112KB dynamic LDS on the pipelined GEMMs (idempotent, capture-safe)
  hipFuncSetAttribute((const void*)gemm8ph_k<0>, hipFuncAttributeMaxDynamicSharedMemorySize, 114688);
  hipFuncSetAttribute((const void*)gemm8ph_k<1>, hipFuncAttributeMaxDynamicSharedMemorySize, 114688);

  // pre-pass
  cvt_f32_bf16_k<<<(Mq * C / 4 + 255) / 256, 256, 0, stream>>>(x, xbf, Mq * C / 4);
  cvt_f32_bf16_k<<<(Mk * CC / 4 + 255) / 256, 256, 0, stream>>>(ctx, ctxbf, Mk * CC / 4);
  transp_bf16_k<<<dim3(C / 32, C / 32), 256, 0, stream>>>(Wq, WqT, C, C);
  transp_bf16_k<<<dim3(CC / 32, C / 32), 256, 0, stream>>>(Wk, WkT, CC, C);
  transp_bf16_k<<<dim3(CC / 32, C / 32), 256, 0, stream>>>(Wv, WvT, CC, C);
  transp_bf16_k<<<dim3(C / 32, C / 32), 256, 0, stream>>>(Wo, WoT, C, C);
  mask_bias_k<<<1, 256, 0, stream>>>(msk, bias, 256);

  // Q projection (4-phase pipelined GEMM, bf16 out)
  gemm8ph_k<0><<<(Mq / 256) * (C / 192), 512, 114688, stream>>>(xbf, WqT, qbf, Mq, C, C);
  // K+V projections merged: split-K=4 f32 partials into d_out scratch, then reduce
  gemm_bt_k<5><<<dim3(Mk / 128, 3072 / 128, 4), 256, 0, stream>>>(ctxbf, WkT, part, Mk, 3072, CC, 1024);
  kv_reduce_k<<<768, 256, 0, stream>>>(part, kbf, vtbf);

  // fused attention
  attn_k<<<dim3(NI / 128, H, B), 256, 0, stream>>>(qbf, kbf, vtbf, bias, aout);

  // output projection (4-phase pipelined GEMM, f32 out)
  gemm8ph_k<1><<<(Mq / 256) * (C / 192), 512, 114688, stream>>>(aout, WoT, out, Mq, C, C);
}